// Round 5
// baseline (464.186 us; speedup 1.0000x reference)
//
#include <hip/hip_runtime.h>
#include <cstdint>

#define HEXP 10.0f
#define HEPS 1e-8f
#define LN2 0.69314718056f
#define RLN2 1.44269504089f

// hardware transcendentals: v_log_f32 computes log2(x), v_exp_f32 computes 2^x
__device__ __forceinline__ float hw_log2(float x) { return __builtin_amdgcn_logf(x); }
__device__ __forceinline__ float hw_exp2(float x) { return __builtin_amdgcn_exp2f(x); }

typedef __bf16 bf16x8 __attribute__((ext_vector_type(8)));
typedef float f32x4 __attribute__((ext_vector_type(4)));

__device__ __forceinline__ unsigned short f2bf(float f) {
  uint32_t u = __float_as_uint(f);
  uint32_t r = (u + 0x7fffu + ((u >> 16) & 1u)) >> 16;
  return (unsigned short)r;
}

__device__ __forceinline__ void gl_lds16(const void* g, void* l) {
  __builtin_amdgcn_global_load_lds(
      (const __attribute__((address_space(1))) void*)g,
      (__attribute__((address_space(3))) void*)l, 16, 0, 0);
}

#define BAR() asm volatile("s_barrier" ::: "memory")
#define VM8() asm volatile("s_waitcnt vmcnt(8)" ::: "memory")

// ---------------- row L2-normalize f32 -> bf16 (D = 1024) ----------------
__global__ __launch_bounds__(256) void k_rownorm(const float* __restrict__ in,
                                                 unsigned short* __restrict__ out,
                                                 int D) {
  const int row = blockIdx.x;
  const int tid = threadIdx.x;
  const float4* inr = (const float4*)(in + (size_t)row * D);
  float4 v = inr[tid];
  float ss = v.x * v.x + v.y * v.y + v.z * v.z + v.w * v.w;
#pragma unroll
  for (int off = 32; off >= 1; off >>= 1) ss += __shfl_xor(ss, off, 64);
  __shared__ float s4[4];
  if ((tid & 63) == 0) s4[tid >> 6] = ss;
  __syncthreads();
  float tot = s4[0] + s4[1] + s4[2] + s4[3];
  float scale = 1.f / fmaxf(sqrtf(tot), 1e-12f);
  ushort4 o;
  o.x = f2bf(v.x * scale);
  o.y = f2bf(v.y * scale);
  o.z = f2bf(v.z * scale);
  o.w = f2bf(v.w * scale);
  ((ushort4*)(out + (size_t)row * D))[tid] = o;
}

// ------------- fused GEMM (xn . wn^T) + logits + per-tile online LSE -------------
// 256x256 tile, 8 waves (2M x 4N). 4 phases per 64-K-tile, counted vmcnt(8)
// (T3+T4), setprio around MFMA (T5). LDS = ring of 32-K half-chunks in
// paired-row layout: elem(r,k) = (r>>1)*64 + (r&1)*32 + k  -> staging is
// linear for global_load_lds AND ds_read_b128 frags hit all 32 banks evenly.
//
// Staging calendar (phase = 4t+ph+1; events = vmcnt(8)+barrier at even phases):
//   ph0 of tile t: stage A[t+1].Kh1   ph1: B[t+1].Kh1 (+event)
//   ph2 of tile t: stage A[t+2].Kh0   ph3: B[t+2].Kh0 (+event)
// Every half certified >=1 phase before first read; every overwrite issued
// after the barrier ending its old content's last read. Hand-verified.
__global__ __launch_bounds__(512, 2) void k_gemm_lse(
    const unsigned short* __restrict__ xnb,
    const unsigned short* __restrict__ wnb,
    const int* __restrict__ tgt,
    float2* __restrict__ parts,
    float* __restrict__ tlp,
    int M, int C, int D, int ntN) {
  __shared__ unsigned short sA[2][2][8192];  // [dbuf][khalf][256 rows x 32 k]
  __shared__ unsigned short sB[2][2][8192];
  __shared__ int s_tgt[256];

  const int ntM = M >> 8;               // 16
  const int nwg = ntM * ntN;            // 2000 (divisible by 8)
  const int orig = blockIdx.x;
  const int cpx = nwg >> 3;
  const int bid = (orig & 7) * cpx + (orig >> 3);   // bijective XCD swizzle
  const int tileM = bid % ntM;
  const int tileN = bid / ntM;
  const int row0 = tileM << 8;
  const int c0 = tileN << 8;

  const int tid = threadIdx.x;
  const int lane = tid & 63;
  const int wid = tid >> 6;
  const int wr = wid >> 2;              // 0..1 : M-half (128 rows)
  const int wc = wid & 3;               // 0..3 : N-quarter (64 cols)
  const int fcol = lane & 15;
  const int kq = lane >> 4;

  if (tid < 256) s_tgt[tid] = tgt[row0 + tid];

  // staging source map: LDS elem e = wid*1024 + l*512 + lane*8
  // -> row = (e>>6)*2 + ((e>>5)&1), col = e & 31 (within the 32-K chunk)
  const int e0 = wid * 1024 + lane * 8;
  const int srow0 = ((e0 >> 6) << 1) + ((e0 >> 5) & 1);
  const int scol0 = e0 & 31;
  const int e1 = e0 + 512;
  const int srow1 = ((e1 >> 6) << 1) + ((e1 >> 5) & 1);
  const int scol1 = e1 & 31;
  const size_t Dz = (size_t)D;
  const int ldst0 = wid * 1024;         // elem offset of this wave's chunk 0
  const int ldst1 = wid * 1024 + 512;

#define STAGE_A(ds, ks, kb)                                                   \
  do {                                                                        \
    gl_lds16(xnb + (size_t)(row0 + srow0) * Dz + (kb) + scol0,                \
             &sA[ds][ks][ldst0]);                                             \
    gl_lds16(xnb + (size_t)(row0 + srow1) * Dz + (kb) + scol1,                \
             &sA[ds][ks][ldst1]);                                             \
  } while (0)
#define STAGE_B(ds, ks, kb)                                                   \
  do {                                                                        \
    gl_lds16(wnb + (size_t)(c0 + srow0) * Dz + (kb) + scol0,                  \
             &sB[ds][ks][ldst0]);                                             \
    gl_lds16(wnb + (size_t)(c0 + srow1) * Dz + (kb) + scol1,                  \
             &sB[ds][ks][ldst1]);                                             \
  } while (0)

  // fragment read offsets (paired-row layout)
  const int aoff = (wr * 64 + (fcol >> 1)) * 64 + (fcol & 1) * 32 + kq * 8;
  const int boff = (wc * 32 + (fcol >> 1)) * 64 + (fcol & 1) * 32 + kq * 8;

  f32x4 acc[8][4];
#pragma unroll
  for (int m = 0; m < 8; ++m)
#pragma unroll
    for (int n = 0; n < 4; ++n) acc[m][n] = (f32x4){0.f, 0.f, 0.f, 0.f};
  bf16x8 af[8];

  const int NT = D >> 6;  // 16 K-tiles of 64

  // prologue: tiles 0 (both halves) + tile 1 Kh0; then event
  STAGE_A(0, 0, 0);
  STAGE_B(0, 0, 0);
  STAGE_A(0, 1, 32);
  STAGE_B(0, 1, 32);
  STAGE_A(1, 0, 64);
  STAGE_B(1, 0, 64);
  VM8();
  BAR();

#define PHASE(d, kh, np, STAGE_STMT, EVT)                                      \
  do {                                                                         \
    bf16x8 bfr0 = *(const bf16x8*)&sB[d][kh][boff + ((np)*2 + 0) * 512];       \
    bf16x8 bfr1 = *(const bf16x8*)&sB[d][kh][boff + ((np)*2 + 1) * 512];       \
    if ((np) == 0) {                                                           \
      _Pragma("unroll") for (int mm = 0; mm < 8; ++mm)                         \
          af[mm] = *(const bf16x8*)&sA[d][kh][aoff + mm * 512];                \
    }                                                                          \
    STAGE_STMT;                                                                \
    BAR();                                                                     \
    __builtin_amdgcn_s_setprio(1);                                             \
    _Pragma("unroll") for (int mm = 0; mm < 8; ++mm) {                         \
      acc[mm][(np)*2 + 0] = __builtin_amdgcn_mfma_f32_16x16x32_bf16(           \
          af[mm], bfr0, acc[mm][(np)*2 + 0], 0, 0, 0);                         \
      acc[mm][(np)*2 + 1] = __builtin_amdgcn_mfma_f32_16x16x32_bf16(           \
          af[mm], bfr1, acc[mm][(np)*2 + 1], 0, 0, 0);                         \
    }                                                                          \
    __builtin_amdgcn_s_setprio(0);                                             \
    if (EVT) VM8();                                                            \
    BAR();                                                                     \
  } while (0)

  for (int t = 0; t < NT; ++t) {
    const int d = t & 1;
    const int dn = d ^ 1;
    PHASE(d, 0, 0, { if (t + 1 < NT) STAGE_A(dn, 1, (t + 1) * 64 + 32); }, 0);
    PHASE(d, 0, 1, { if (t + 1 < NT) STAGE_B(dn, 1, (t + 1) * 64 + 32); }, 1);
    PHASE(d, 1, 0, { if (t + 2 < NT) STAGE_A(d, 0, (t + 2) * 64); }, 0);
    PHASE(d, 1, 1, { if (t + 2 < NT) STAGE_B(d, 0, (t + 2) * 64); }, 1);
  }

  // epilogue: lp = -10*ln2*log2(sqrt(max(2-2s,0))+eps); per-row (max,sumexp)
  // C/D: col = lane&15 (fcol), row = kq*4 + j within each 16x16 fragment
#pragma unroll
  for (int m = 0; m < 8; ++m) {
#pragma unroll
    for (int j = 0; j < 4; ++j) {
      const int rl = wr * 128 + m * 16 + kq * 4 + j;
      const int grow = row0 + rl;
      const int trow = s_tgt[rl];
      float lpv[4];
      float vmax = -3.4e38f;
#pragma unroll
      for (int n = 0; n < 4; ++n) {
        float s = acc[m][n][j];
        float dd = sqrtf(fmaxf(2.f - 2.f * s, 0.f));
        float lp = (-HEXP * LN2) * hw_log2(dd + HEPS);
        lpv[n] = lp;
        vmax = fmaxf(vmax, lp);
        int col = c0 + wc * 64 + n * 16 + fcol;
        if (col == trow) tlp[grow] = lp;
      }
#pragma unroll
      for (int off = 8; off >= 1; off >>= 1)
        vmax = fmaxf(vmax, __shfl_xor(vmax, off, 64));
      float se = 0.f;
#pragma unroll
      for (int n = 0; n < 4; ++n) se += hw_exp2((lpv[n] - vmax) * RLN2);
#pragma unroll
      for (int off = 8; off >= 1; off >>= 1) se += __shfl_xor(se, off, 64);
      if (fcol == 0)
        parts[(size_t)grow * (ntN * 4) + tileN * 4 + wc] = make_float2(vmax, se);
    }
  }
}

// ---------------- per-row LSE over partials + per-row loss ----------------
__global__ __launch_bounds__(256) void k_combine(const float2* __restrict__ parts,
                                                 const float* __restrict__ tlp,
                                                 float* __restrict__ rloss, int P) {
  const int row = blockIdx.x;
  const int tid = threadIdx.x;
  const float2* p = parts + (size_t)row * P;
  float m = -3.4e38f;
  for (int i = tid; i < P; i += 256) m = fmaxf(m, p[i].x);
#pragma unroll
  for (int off = 32; off >= 1; off >>= 1) m = fmaxf(m, __shfl_xor(m, off, 64));
  __shared__ float sm[4];
  __shared__ float ssum[4];
  if ((tid & 63) == 0) sm[tid >> 6] = m;
  __syncthreads();
  m = fmaxf(fmaxf(sm[0], sm[1]), fmaxf(sm[2], sm[3]));
  float s = 0.f;
  for (int i = tid; i < P; i += 256) s += hw_exp2((p[i].x - m) * RLN2) * p[i].y;
#pragma unroll
  for (int off = 32; off >= 1; off >>= 1) s += __shfl_xor(s, off, 64);
  if ((tid & 63) == 0) ssum[tid >> 6] = s;
  __syncthreads();
  if (tid == 0) {
    float tot = ssum[0] + ssum[1] + ssum[2] + ssum[3];
    float lse = m + hw_log2(tot) * LN2;
    float pt = hw_exp2((tlp[row] - lse) * RLN2);
    rloss[row] = -hw_log2(pt + 1e-8f) * LN2;
  }
}

// ---------------- mean over rows ----------------
__global__ __launch_bounds__(256) void k_mean(const float* __restrict__ rloss,
                                              float* __restrict__ out, int B) {
  const int tid = threadIdx.x;
  double s = 0.0;
  for (int i = tid; i < B; i += 256) s += (double)rloss[i];
#pragma unroll
  for (int off = 32; off >= 1; off >>= 1) s += __shfl_xor(s, off, 64);
  __shared__ double sd[4];
  if ((tid & 63) == 0) sd[tid >> 6] = s;
  __syncthreads();
  if (tid == 0) out[0] = (float)((sd[0] + sd[1] + sd[2] + sd[3]) / (double)B);
}

extern "C" void kernel_launch(void* const* d_in, const int* in_sizes, int n_in,
                              void* d_out, int out_size, void* d_ws, size_t ws_size,
                              hipStream_t stream) {
  const float* x = (const float*)d_in[0];
  const float* w = (const float*)d_in[1];
  const int* tg = (const int*)d_in[2];
  const int B = in_sizes[2];
  const int D = in_sizes[0] / B;       // 1024
  const int C = in_sizes[1] / D;       // 32000
  const int ntN = C / 256;             // 125

  char* ws = (char*)d_ws;
  unsigned short* xnb = (unsigned short*)ws;                 // B*D bf16
  unsigned short* wnb = xnb + (size_t)B * D;                 // C*D bf16
  size_t off = ((size_t)B * D + (size_t)C * D) * sizeof(unsigned short);
  off = (off + 255) & ~(size_t)255;
  float2* parts = (float2*)(ws + off);                       // B * ntN * 4
  off += (size_t)B * ntN * 4 * sizeof(float2);
  float* tlp = (float*)(ws + off);                           // B
  off += (size_t)B * sizeof(float);
  float* rloss = (float*)(ws + off);                         // B

  k_rownorm<<<B, 256, 0, stream>>>(x, xnb, D);
  k_rownorm<<<C, 256, 0, stream>>>(w, wnb, D);
  k_gemm_lse<<<(B / 256) * ntN, 512, 0, stream>>>(xnb, wnb, tg, parts, tlp, B, C, D, ntN);
  k_combine<<<B, 256, 0, stream>>>(parts, tlp, rloss, ntN * 4);
  k_mean<<<1, 256, 0, stream>>>(rloss, (float*)d_out, B);
}

// Round 6
// 448.513 us; speedup vs baseline: 1.0349x; 1.0349x over previous
//
#include <hip/hip_runtime.h>
#include <cstdint>

#define HEXP 10.0f
#define HEPS 1e-8f
#define LN2 0.69314718056f
#define RLN2 1.44269504089f

// hardware transcendentals: v_log_f32 computes log2(x), v_exp_f32 computes 2^x
__device__ __forceinline__ float hw_log2(float x) { return __builtin_amdgcn_logf(x); }
__device__ __forceinline__ float hw_exp2(float x) { return __builtin_amdgcn_exp2f(x); }

typedef __bf16 bf16x8 __attribute__((ext_vector_type(8)));
typedef float f32x4 __attribute__((ext_vector_type(4)));

__device__ __forceinline__ unsigned short f2bf(float f) {
  uint32_t u = __float_as_uint(f);
  uint32_t r = (u + 0x7fffu + ((u >> 16) & 1u)) >> 16;
  return (unsigned short)r;
}

__device__ __forceinline__ void gl_lds16(const void* g, void* l) {
  __builtin_amdgcn_global_load_lds(
      (const __attribute__((address_space(1))) void*)g,
      (__attribute__((address_space(3))) void*)l, 16, 0, 0);
}

#define BAR() asm volatile("s_barrier" ::: "memory")
#define VM8() asm volatile("s_waitcnt vmcnt(8)" ::: "memory")

// ---------------- row L2-normalize f32 -> bf16 (D = 1024) ----------------
__global__ __launch_bounds__(256) void k_rownorm(const float* __restrict__ in,
                                                 unsigned short* __restrict__ out,
                                                 int D) {
  const int row = blockIdx.x;
  const int tid = threadIdx.x;
  const float4* inr = (const float4*)(in + (size_t)row * D);
  float4 v = inr[tid];
  float ss = v.x * v.x + v.y * v.y + v.z * v.z + v.w * v.w;
#pragma unroll
  for (int off = 32; off >= 1; off >>= 1) ss += __shfl_xor(ss, off, 64);
  __shared__ float s4[4];
  if ((tid & 63) == 0) s4[tid >> 6] = ss;
  __syncthreads();
  float tot = s4[0] + s4[1] + s4[2] + s4[3];
  float scale = 1.f / fmaxf(sqrtf(tot), 1e-12f);
  ushort4 o;
  o.x = f2bf(v.x * scale);
  o.y = f2bf(v.y * scale);
  o.z = f2bf(v.z * scale);
  o.w = f2bf(v.w * scale);
  ((ushort4*)(out + (size_t)row * D))[tid] = o;
}

// ------------- fused GEMM (xn . wn^T) + logits + per-tile online LSE -------------
// 256x256 tile, 8 waves (2M x 4N). 4 phases per 64-K-tile, counted vmcnt(8)
// (T3+T4), setprio around MFMA (T5).
//
// Chunk layout (per [256r x 32k] 16KB chunk), conflict-free under the
// quarter-wave model that matched R4 (0 conflicts) and R5 (8-way, 2.46e7):
//   byte(r,k) = (r>>1)*128 + (r&1)*64 + ((k>>3) ^ ((r>>1)&3))*16 + (k&7)*2
// Read: 16-lane group (fixed kq) hits slots ((fcol&1), kq^((fcol>>1)&3))
//   -> 8 distinct 16B slots x 2 lanes = 2-way = free (m136).
// Write: global_load_lds linear dest; per-lane inverse-swizzled global src
//   (rule #21). Decode of dest byte b: rp=b>>7, r=rp*2+((b>>6)&1),
//   kg=((b>>4)&3)^(rp&3); lane sources global (r, kg*8..kg*8+7). Round-trip
//   verified against the read formula.
//
// Staging calendar (validated R5, absmax 0): per tile t:
//   ph0: stage A[t+1].h1   ph1: stage B[t+1].h1, then VM8
//   ph2: stage A[t+2].h0   ph3: stage B[t+2].h0, then VM8
// At every first-read, the chunk is older than the newest-8 window -> certified.
__global__ __launch_bounds__(512, 2) void k_gemm_lse(
    const unsigned short* __restrict__ xnb,
    const unsigned short* __restrict__ wnb,
    const int* __restrict__ tgt,
    float2* __restrict__ parts,
    float* __restrict__ tlp,
    int M, int C, int D, int ntN) {
  __shared__ unsigned short sA[2][2][8192];  // [dbuf][khalf][256r x 32k chunk]
  __shared__ unsigned short sB[2][2][8192];
  __shared__ int s_tgt[256];

  const int ntM = M >> 8;               // 16
  const int nwg = ntM * ntN;            // 2000 (divisible by 8)
  const int orig = blockIdx.x;
  const int cpx = nwg >> 3;
  const int bid = (orig & 7) * cpx + (orig >> 3);   // bijective XCD swizzle
  const int tileM = bid % ntM;
  const int tileN = bid / ntM;
  const int row0 = tileM << 8;
  const int c0 = tileN << 8;

  const int tid = threadIdx.x;
  const int lane = tid & 63;
  const int wid = tid >> 6;
  const int wr = wid >> 2;              // 0..1 : M-half (128 rows)
  const int wc = wid & 3;               // 0..3 : N-quarter (64 cols)
  const int fcol = lane & 15;
  const int kq = lane >> 4;

  if (tid < 256) s_tgt[tid] = tgt[row0 + tid];

  // staging source decode (lane writes 16B at chunk byte b = wid*2048+sub*1024+lane*16)
  const int b0 = wid * 2048 + lane * 16;
  const int rp0 = b0 >> 7;
  const int srow0 = rp0 * 2 + ((b0 >> 6) & 1);
  const int scol0 = ((((b0 >> 4) & 3) ^ (rp0 & 3)) << 3);
  const int b1 = b0 + 1024;
  const int rp1 = b1 >> 7;
  const int srow1 = rp1 * 2 + ((b1 >> 6) & 1);
  const int scol1 = ((((b1 >> 4) & 3) ^ (rp1 & 3)) << 3);
  const size_t Dz = (size_t)D;
  const int ldst0 = wid * 1024;         // elem offset of wave's sub-chunk 0
  const int ldst1 = wid * 1024 + 512;

#define STAGE_A(ds, ks, kb)                                                   \
  do {                                                                        \
    gl_lds16(xnb + (size_t)(row0 + srow0) * Dz + (kb) + scol0,                \
             &sA[ds][ks][ldst0]);                                             \
    gl_lds16(xnb + (size_t)(row0 + srow1) * Dz + (kb) + scol1,                \
             &sA[ds][ks][ldst1]);                                             \
  } while (0)
#define STAGE_B(ds, ks, kb)                                                   \
  do {                                                                        \
    gl_lds16(wnb + (size_t)(c0 + srow0) * Dz + (kb) + scol0,                  \
             &sB[ds][ks][ldst0]);                                             \
    gl_lds16(wnb + (size_t)(c0 + srow1) * Dz + (kb) + scol1,                  \
             &sB[ds][ks][ldst1]);                                             \
  } while (0)

  // fragment read offsets (elem units); per-m / per-n stride stays 512
  const int xorq = (fcol >> 1) & 3;
  const int aoff = (wr * 64 + (fcol >> 1)) * 64 + (fcol & 1) * 32 + ((kq ^ xorq) << 3);
  const int boff = (wc * 32 + (fcol >> 1)) * 64 + (fcol & 1) * 32 + ((kq ^ xorq) << 3);

  f32x4 acc[8][4];
#pragma unroll
  for (int m = 0; m < 8; ++m)
#pragma unroll
    for (int n = 0; n < 4; ++n) acc[m][n] = (f32x4){0.f, 0.f, 0.f, 0.f};
  bf16x8 af[8];

  const int NT = D >> 6;  // 16 K-tiles of 64

  // prologue: tile 0 (both halves) + tile 1 h0; then event
  STAGE_A(0, 0, 0);
  STAGE_B(0, 0, 0);
  STAGE_A(0, 1, 32);
  STAGE_B(0, 1, 32);
  STAGE_A(1, 0, 64);
  STAGE_B(1, 0, 64);
  VM8();
  BAR();

#define PHASE(d, kh, np, STAGE_STMT, EVT)                                      \
  do {                                                                         \
    bf16x8 bfr0 = *(const bf16x8*)&sB[d][kh][boff + ((np)*2 + 0) * 512];       \
    bf16x8 bfr1 = *(const bf16x8*)&sB[d][kh][boff + ((np)*2 + 1) * 512];       \
    if ((np) == 0) {                                                           \
      _Pragma("unroll") for (int mm = 0; mm < 8; ++mm)                         \
          af[mm] = *(const bf16x8*)&sA[d][kh][aoff + mm * 512];                \
    }                                                                          \
    STAGE_STMT;                                                                \
    BAR();                                                                     \
    __builtin_amdgcn_s_setprio(1);                                             \
    _Pragma("unroll") for (int mm = 0; mm < 8; ++mm) {                         \
      acc[mm][(np)*2 + 0] = __builtin_amdgcn_mfma_f32_16x16x32_bf16(           \
          af[mm], bfr0, acc[mm][(np)*2 + 0], 0, 0, 0);                         \
      acc[mm][(np)*2 + 1] = __builtin_amdgcn_mfma_f32_16x16x32_bf16(           \
          af[mm], bfr1, acc[mm][(np)*2 + 1], 0, 0, 0);                         \
    }                                                                          \
    __builtin_amdgcn_s_setprio(0);                                             \
    if (EVT) VM8();                                                            \
    BAR();                                                                     \
  } while (0)

  for (int t = 0; t < NT; ++t) {
    const int d = t & 1;
    const int dn = d ^ 1;
    PHASE(d, 0, 0, { if (t + 1 < NT) STAGE_A(dn, 1, (t + 1) * 64 + 32); }, 0);
    PHASE(d, 0, 1, { if (t + 1 < NT) STAGE_B(dn, 1, (t + 1) * 64 + 32); }, 1);
    PHASE(d, 1, 0, { if (t + 2 < NT) STAGE_A(d, 0, (t + 2) * 64); }, 0);
    PHASE(d, 1, 1, { if (t + 2 < NT) STAGE_B(d, 0, (t + 2) * 64); }, 1);
  }

  // epilogue: lp = -10*ln2*log2(sqrt(max(2-2s,0))+eps); per-row (max,sumexp)
  // C/D: col = lane&15 (fcol), row = kq*4 + j within each 16x16 fragment
#pragma unroll
  for (int m = 0; m < 8; ++m) {
#pragma unroll
    for (int j = 0; j < 4; ++j) {
      const int rl = wr * 128 + m * 16 + kq * 4 + j;
      const int grow = row0 + rl;
      const int trow = s_tgt[rl];
      float lpv[4];
      float vmax = -3.4e38f;
#pragma unroll
      for (int n = 0; n < 4; ++n) {
        float s = acc[m][n][j];
        float dd = sqrtf(fmaxf(2.f - 2.f * s, 0.f));
        float lp = (-HEXP * LN2) * hw_log2(dd + HEPS);
        lpv[n] = lp;
        vmax = fmaxf(vmax, lp);
        int col = c0 + wc * 64 + n * 16 + fcol;
        if (col == trow) tlp[grow] = lp;
      }
#pragma unroll
      for (int off = 8; off >= 1; off >>= 1)
        vmax = fmaxf(vmax, __shfl_xor(vmax, off, 64));
      float se = 0.f;
#pragma unroll
      for (int n = 0; n < 4; ++n) se += hw_exp2((lpv[n] - vmax) * RLN2);
#pragma unroll
      for (int off = 8; off >= 1; off >>= 1) se += __shfl_xor(se, off, 64);
      if (fcol == 0)
        parts[(size_t)grow * (ntN * 4) + tileN * 4 + wc] = make_float2(vmax, se);
    }
  }
}

// ---------------- per-row LSE over partials + per-row loss ----------------
__global__ __launch_bounds__(256) void k_combine(const float2* __restrict__ parts,
                                                 const float* __restrict__ tlp,
                                                 float* __restrict__ rloss, int P) {
  const int row = blockIdx.x;
  const int tid = threadIdx.x;
  const float2* p = parts + (size_t)row * P;
  float m = -3.4e38f;
  for (int i = tid; i < P; i += 256) m = fmaxf(m, p[i].x);
#pragma unroll
  for (int off = 32; off >= 1; off >>= 1) m = fmaxf(m, __shfl_xor(m, off, 64));
  __shared__ float sm[4];
  __shared__ float ssum[4];
  if ((tid & 63) == 0) sm[tid >> 6] = m;
  __syncthreads();
  m = fmaxf(fmaxf(sm[0], sm[1]), fmaxf(sm[2], sm[3]));
  float s = 0.f;
  for (int i = tid; i < P; i += 256) s += hw_exp2((p[i].x - m) * RLN2) * p[i].y;
#pragma unroll
  for (int off = 32; off >= 1; off >>= 1) s += __shfl_xor(s, off, 64);
  if ((tid & 63) == 0) ssum[tid >> 6] = s;
  __syncthreads();
  if (tid == 0) {
    float tot = ssum[0] + ssum[1] + ssum[2] + ssum[3];
    float lse = m + hw_log2(tot) * LN2;
    float pt = hw_exp2((tlp[row] - lse) * RLN2);
    rloss[row] = -hw_log2(pt + 1e-8f) * LN2;
  }
}

// ---------------- mean over rows ----------------
__global__ __launch_bounds__(256) void k_mean(const float* __restrict__ rloss,
                                              float* __restrict__ out, int B) {
  const int tid = threadIdx.x;
  double s = 0.0;
  for (int i = tid; i < B; i += 256) s += (double)rloss[i];
#pragma unroll
  for (int off = 32; off >= 1; off >>= 1) s += __shfl_xor(s, off, 64);
  __shared__ double sd[4];
  if ((tid & 63) == 0) sd[tid >> 6] = s;
  __syncthreads();
  if (tid == 0) out[0] = (float)((sd[0] + sd[1] + sd[2] + sd[3]) / (double)B);
}

extern "C" void kernel_launch(void* const* d_in, const int* in_sizes, int n_in,
                              void* d_out, int out_size, void* d_ws, size_t ws_size,
                              hipStream_t stream) {
  const float* x = (const float*)d_in[0];
  const float* w = (const float*)d_in[1];
  const int* tg = (const int*)d_in[2];
  const int B = in_sizes[2];
  const int D = in_sizes[0] / B;       // 1024
  const int C = in_sizes[1] / D;       // 32000
  const int ntN = C / 256;             // 125

  char* ws = (char*)d_ws;
  unsigned short* xnb = (unsigned short*)ws;                 // B*D bf16
  unsigned short* wnb = xnb + (size_t)B * D;                 // C*D bf16
  size_t off = ((size_t)B * D + (size_t)C * D) * sizeof(unsigned short);
  off = (off + 255) & ~(size_t)255;
  float2* parts = (float2*)(ws + off);                       // B * ntN * 4
  off += (size_t)B * ntN * 4 * sizeof(float2);
  float* tlp = (float*)(ws + off);                           // B
  off += (size_t)B * sizeof(float);
  float* rloss = (float*)(ws + off);                         // B

  k_rownorm<<<B, 256, 0, stream>>>(x, xnb, D);
  k_rownorm<<<C, 256, 0, stream>>>(w, wnb, D);
  k_gemm_lse<<<(B / 256) * ntN, 512, 0, stream>>>(xnb, wnb, tg, parts, tlp, B, C, D, ntN);
  k_combine<<<B, 256, 0, stream>>>(parts, tlp, rloss, ntN * 4);
  k_mean<<<1, 256, 0, stream>>>(rloss, (float*)d_out, B);
}

// Round 7
// 423.252 us; speedup vs baseline: 1.0967x; 1.0597x over previous
//
#include <hip/hip_runtime.h>
#include <cstdint>

#define HEXP 10.0f
#define HEPS 1e-8f
#define LN2 0.69314718056f
#define RLN2 1.44269504089f

// hardware transcendentals: v_log_f32 computes log2(x), v_exp_f32 computes 2^x
__device__ __forceinline__ float hw_log2(float x) { return __builtin_amdgcn_logf(x); }
__device__ __forceinline__ float hw_exp2(float x) { return __builtin_amdgcn_exp2f(x); }

typedef float f32x4 __attribute__((ext_vector_type(4)));

__device__ __forceinline__ void gl_lds16(const void* g, void* l) {
  __builtin_amdgcn_global_load_lds(
      (const __attribute__((address_space(1))) void*)g,
      (__attribute__((address_space(3))) void*)l, 16, 0, 0);
}

#define BAR() asm volatile("s_barrier" ::: "memory")
#define VM8() asm volatile("s_waitcnt vmcnt(8)" ::: "memory")
#define VM4() asm volatile("s_waitcnt vmcnt(4)" ::: "memory")
#define VM0() asm volatile("s_waitcnt vmcnt(0)" ::: "memory")

// ------------- row L2-normalize f32 -> fp8 e4m3 scaled by 16 (D = 1024) -------------
__global__ __launch_bounds__(256) void k_rownorm(const float* __restrict__ in,
                                                 unsigned char* __restrict__ out,
                                                 int D) {
  const int row = blockIdx.x;
  const int tid = threadIdx.x;
  const float4* inr = (const float4*)(in + (size_t)row * D);
  float4 v = inr[tid];
  float ss = v.x * v.x + v.y * v.y + v.z * v.z + v.w * v.w;
#pragma unroll
  for (int off = 32; off >= 1; off >>= 1) ss += __shfl_xor(ss, off, 64);
  __shared__ float s4[4];
  if ((tid & 63) == 0) s4[tid >> 6] = ss;
  __syncthreads();
  float tot = s4[0] + s4[1] + s4[2] + s4[3];
  // scale by 16: typical |16*xn_i| ~ 0.5, max 16 << 448 (e4m3 sat). GEMM result = 256*s.
  float scale = 16.f / fmaxf(sqrtf(tot), 1e-12f);
  int w0 = __builtin_amdgcn_cvt_pk_fp8_f32(v.x * scale, v.y * scale, 0, false);
  w0 = __builtin_amdgcn_cvt_pk_fp8_f32(v.z * scale, v.w * scale, w0, true);
  ((int*)(out + (size_t)row * D))[tid] = w0;
}

// ------------- fused fp8 GEMM (xn . wn^T) + logits + per-tile online LSE -------------
// 256x256 tile, 8 waves (2M x 4N), BK=64. LDS = 3-deep ring of 16KB fp8 chunks
// per matrix (96 KiB). 2-tile prefetch distance, 1 barrier/K-tile, counted
// vmcnt(8) (tail 4/0) -> stage-to-use slack ~2 tiles; no vmcnt(0) drains in loop.
//
// Chunk layout ([256 r x 64 k] fp8, 16KB):
//   byte(r,k) = r*64 + ((k>>3) ^ e(r))*8 + (k&7),  e(r) = ((r>>1)&3)<<1  (even!)
// Read (ds_read_b64, 16-lane quarter-wave, fixed kq): slot = (kq+4kk) ^ e(fcol)
//   -> (parity, slot) covers 8 bank-pair positions x 2 lanes = 2-way = free (m136).
// Write (rule #21 both-sides): gl_lds16 dest linear; lane ln sources global
//   row = seg*16 + (ln>>2), kblk = 2*((ln&3) ^ ((ln>>3)&3))  (even -> the 16B
//   global read covers kblk,kblk+1 ascending = contiguous & 16B-aligned).
//   Round-trip: dest byte b = seg*1024+ln*16 -> r=b>>6=seg*16+(ln>>2);
//   u'=(b>>3)&7=2(ln&3); k1=u'^e(r)=2((ln&3)^((ln>>3)&3)). Matches source.
__global__ __launch_bounds__(512, 2) void k_gemm_lse(
    const unsigned char* __restrict__ xnb,
    const unsigned char* __restrict__ wnb,
    const int* __restrict__ tgt,
    float2* __restrict__ parts,
    float* __restrict__ tlp,
    int M, int C, int D, int ntN) {
  __shared__ __align__(16) unsigned char sA[3][16384];
  __shared__ __align__(16) unsigned char sB[3][16384];
  __shared__ int s_tgt[256];

  const int ntM = M >> 8;               // 16
  const int nwg = ntM * ntN;            // 2000 (divisible by 8)
  const int orig = blockIdx.x;
  const int cpx = nwg >> 3;
  const int bid = (orig & 7) * cpx + (orig >> 3);   // bijective XCD swizzle
  const int tileM = bid % ntM;
  const int tileN = bid / ntM;
  const int row0 = tileM << 8;
  const int c0 = tileN << 8;

  const int tid = threadIdx.x;
  const int lane = tid & 63;
  const int wid = tid >> 6;
  const int wr = wid >> 2;              // 0..1 : M-half (128 rows)
  const int wc = wid & 3;               // 0..3 : N-quarter (64 cols)
  const int fcol = lane & 15;
  const int kq = lane >> 4;

  if (tid < 256) s_tgt[tid] = tgt[row0 + tid];

  // staging lane constants
  const int srow_l = lane >> 2;                                  // 0..15 within seg
  const int scol_l = (((lane & 3) ^ ((lane >> 3) & 3)) << 4);    // byte offset in row
  const int lane16 = lane << 4;
  const size_t Dz = (size_t)D;  // row stride in BYTES (fp8)

#define STAGE(dst, mat, rb, kb)                                                \
  do {                                                                         \
    gl_lds16((mat) + (size_t)((rb) + (wid << 4) + srow_l) * Dz + (kb) + scol_l,\
             (dst) + (wid << 10) + lane16);                                    \
    gl_lds16((mat) + (size_t)((rb) + 128 + (wid << 4) + srow_l) * Dz + (kb) +  \
                 scol_l,                                                       \
             (dst) + 8192 + (wid << 10) + lane16);                             \
  } while (0)

  // fragment read bases (bytes). e(r) for fragment rows == ((fcol>>1)&3)<<1.
  const int eL = ((fcol >> 1) & 3) << 1;
  const int abase = (wr * 128 + fcol) * 64 + ((kq ^ eL) << 3);
  const int bbase = (wc * 64 + fcol) * 64 + ((kq ^ eL) << 3);
  // kk=1 (k in [32,64)): slot ^= 4 -> byte addr ^= 32.

  f32x4 acc[8][4];
#pragma unroll
  for (int m = 0; m < 8; ++m)
#pragma unroll
    for (int n = 0; n < 4; ++n) acc[m][n] = (f32x4){0.f, 0.f, 0.f, 0.f};

  const int NT = D >> 6;  // 16 K-tiles of 64 bytes

  // prologue: stage tiles 0 and 1 into rings 0,1 (8 gl_lds/wave outstanding)
  STAGE(sA[0], xnb, row0, 0);
  STAGE(sB[0], wnb, c0, 0);
  STAGE(sA[1], xnb, row0, 64);
  STAGE(sB[1], wnb, c0, 64);

  for (int t = 0; t < NT; ++t) {
    const int rb = t % 3;
    const int rs = (t + 2) % 3;
    // BAR: all waves done reading ring rs's old content (consumed at tile t-1);
    // no vmcnt drain (asm barrier, not __syncthreads).
    BAR();
    if (t + 2 < NT) {
      STAGE(sA[rs], xnb, row0, (t + 2) * 64);
      STAGE(sB[rs], wnb, c0, (t + 2) * 64);
    }
    // counted certification of tile t's chunks (issued 2 tiles ago):
    // allow pending = stages of tiles t+1 and t+2 only.
    if (t + 2 < NT) VM8();
    else if (t + 1 < NT) VM4();
    else VM0();

    const unsigned char* pA = sA[rb];
    const unsigned char* pB = sB[rb];
    long bv[4][2];
#pragma unroll
    for (int n = 0; n < 4; ++n) {
      const int ba = bbase + n * 1024;
      bv[n][0] = *(const long*)(pB + ba);
      bv[n][1] = *(const long*)(pB + (ba ^ 32));
    }
#pragma unroll
    for (int mh = 0; mh < 2; ++mh) {
      long av[4][2];
#pragma unroll
      for (int mm = 0; mm < 4; ++mm) {
        const int aa = abase + (mh * 4 + mm) * 1024;
        av[mm][0] = *(const long*)(pA + aa);
        av[mm][1] = *(const long*)(pA + (aa ^ 32));
      }
      __builtin_amdgcn_s_setprio(1);
#pragma unroll
      for (int mm = 0; mm < 4; ++mm)
#pragma unroll
        for (int n = 0; n < 4; ++n) {
          acc[mh * 4 + mm][n] = __builtin_amdgcn_mfma_f32_16x16x32_fp8_fp8(
              av[mm][0], bv[n][0], acc[mh * 4 + mm][n], 0, 0, 0);
          acc[mh * 4 + mm][n] = __builtin_amdgcn_mfma_f32_16x16x32_fp8_fp8(
              av[mm][1], bv[n][1], acc[mh * 4 + mm][n], 0, 0, 0);
        }
      __builtin_amdgcn_s_setprio(0);
    }
  }

  // epilogue: s = acc/256 (inputs scaled 16x); lp = -10*ln2*log2(sqrt(max(2-2s,0))+eps)
  // C/D: col = lane&15 (fcol), row = kq*4 + j within each 16x16 fragment
#pragma unroll
  for (int m = 0; m < 8; ++m) {
#pragma unroll
    for (int j = 0; j < 4; ++j) {
      const int rl = wr * 128 + m * 16 + kq * 4 + j;
      const int grow = row0 + rl;
      const int trow = s_tgt[rl];
      float lpv[4];
      float vmax = -3.4e38f;
#pragma unroll
      for (int n = 0; n < 4; ++n) {
        float s2 = acc[m][n][j] * (1.f / 128.f);  // = 2*s
        float dd = sqrtf(fmaxf(2.f - s2, 0.f));
        float lp = (-HEXP * LN2) * hw_log2(dd + HEPS);
        lpv[n] = lp;
        vmax = fmaxf(vmax, lp);
        int col = c0 + wc * 64 + n * 16 + fcol;
        if (col == trow) tlp[grow] = lp;
      }
#pragma unroll
      for (int off = 8; off >= 1; off >>= 1)
        vmax = fmaxf(vmax, __shfl_xor(vmax, off, 64));
      float se = 0.f;
#pragma unroll
      for (int n = 0; n < 4; ++n) se += hw_exp2((lpv[n] - vmax) * RLN2);
#pragma unroll
      for (int off = 8; off >= 1; off >>= 1) se += __shfl_xor(se, off, 64);
      if (fcol == 0)
        parts[(size_t)grow * (ntN * 4) + tileN * 4 + wc] = make_float2(vmax, se);
    }
  }
}

// ---------------- per-row LSE over partials + per-row loss ----------------
__global__ __launch_bounds__(256) void k_combine(const float2* __restrict__ parts,
                                                 const float* __restrict__ tlp,
                                                 float* __restrict__ rloss, int P) {
  const int row = blockIdx.x;
  const int tid = threadIdx.x;
  const float2* p = parts + (size_t)row * P;
  float m = -3.4e38f;
  for (int i = tid; i < P; i += 256) m = fmaxf(m, p[i].x);
#pragma unroll
  for (int off = 32; off >= 1; off >>= 1) m = fmaxf(m, __shfl_xor(m, off, 64));
  __shared__ float sm[4];
  __shared__ float ssum[4];
  if ((tid & 63) == 0) sm[tid >> 6] = m;
  __syncthreads();
  m = fmaxf(fmaxf(sm[0], sm[1]), fmaxf(sm[2], sm[3]));
  float s = 0.f;
  for (int i = tid; i < P; i += 256) s += hw_exp2((p[i].x - m) * RLN2) * p[i].y;
#pragma unroll
  for (int off = 32; off >= 1; off >>= 1) s += __shfl_xor(s, off, 64);
  if ((tid & 63) == 0) ssum[tid >> 6] = s;
  __syncthreads();
  if (tid == 0) {
    float tot = ssum[0] + ssum[1] + ssum[2] + ssum[3];
    float lse = m + hw_log2(tot) * LN2;
    float pt = hw_exp2((tlp[row] - lse) * RLN2);
    rloss[row] = -hw_log2(pt + 1e-8f) * LN2;
  }
}

// ---------------- mean over rows ----------------
__global__ __launch_bounds__(256) void k_mean(const float* __restrict__ rloss,
                                              float* __restrict__ out, int B) {
  const int tid = threadIdx.x;
  double s = 0.0;
  for (int i = tid; i < B; i += 256) s += (double)rloss[i];
#pragma unroll
  for (int off = 32; off >= 1; off >>= 1) s += __shfl_xor(s, off, 64);
  __shared__ double sd[4];
  if ((tid & 63) == 0) sd[tid >> 6] = s;
  __syncthreads();
  if (tid == 0) out[0] = (float)((sd[0] + sd[1] + sd[2] + sd[3]) / (double)B);
}

extern "C" void kernel_launch(void* const* d_in, const int* in_sizes, int n_in,
                              void* d_out, int out_size, void* d_ws, size_t ws_size,
                              hipStream_t stream) {
  const float* x = (const float*)d_in[0];
  const float* w = (const float*)d_in[1];
  const int* tg = (const int*)d_in[2];
  const int B = in_sizes[2];
  const int D = in_sizes[0] / B;       // 1024
  const int C = in_sizes[1] / D;       // 32000
  const int ntN = C / 256;             // 125

  char* ws = (char*)d_ws;
  unsigned char* xnb = (unsigned char*)ws;                   // B*D fp8
  unsigned char* wnb = xnb + (size_t)B * D;                  // C*D fp8
  size_t off = (size_t)B * D + (size_t)C * D;
  off = (off + 255) & ~(size_t)255;
  float2* parts = (float2*)(ws + off);                       // B * ntN * 4
  off += (size_t)B * ntN * 4 * sizeof(float2);
  float* tlp = (float*)(ws + off);                           // B
  off += (size_t)B * sizeof(float);
  float* rloss = (float*)(ws + off);                         // B

  k_rownorm<<<B, 256, 0, stream>>>(x, xnb, D);
  k_rownorm<<<C, 256, 0, stream>>>(w, wnb, D);
  k_gemm_lse<<<(B / 256) * ntN, 512, 0, stream>>>(xnb, wnb, tg, parts, tlp, B, C, D, ntN);
  k_combine<<<B, 256, 0, stream>>>(parts, tlp, rloss, ntN * 4);
  k_mean<<<1, 256, 0, stream>>>(rloss, (float*)d_out, B);
}

// Round 8
// 350.304 us; speedup vs baseline: 1.3251x; 1.2082x over previous
//
#include <hip/hip_runtime.h>
#include <cstdint>

#define HEXP 10.0f
#define LN2 0.69314718056f
#define RLN2 1.44269504089f

__device__ __forceinline__ float hw_log2(float x) { return __builtin_amdgcn_logf(x); }
__device__ __forceinline__ float hw_exp2(float x) { return __builtin_amdgcn_exp2f(x); }
__device__ __forceinline__ float hw_rcp(float x) { return __builtin_amdgcn_rcpf(x); }

typedef float f32x4 __attribute__((ext_vector_type(4)));
typedef long l2v __attribute__((ext_vector_type(2)));

__device__ __forceinline__ void gl_lds16(const void* g, void* l) {
  __builtin_amdgcn_global_load_lds(
      (const __attribute__((address_space(1))) void*)g,
      (__attribute__((address_space(3))) void*)l, 16, 0, 0);
}

#define BAR() asm volatile("s_barrier" ::: "memory")
#define VM4() asm volatile("s_waitcnt vmcnt(4)" ::: "memory")
#define VM0() asm volatile("s_waitcnt vmcnt(0)" ::: "memory")

// ------- row L2-normalize f32 -> fp8 e4m3 (x16), FRAG-PACKED k-layout -------
// Within each 64-k block: byte pos = kq*16 + kh*8 + j for k = kh*32 + kq*8 + j.
// So each 16B unit at kq*16 is exactly the MFMA fragment pair {kh0, kh1} for kq.
__global__ __launch_bounds__(256) void k_rownorm(const float* __restrict__ in,
                                                 unsigned char* __restrict__ out,
                                                 int D) {
  const int row = blockIdx.x;
  const int tid = threadIdx.x;
  const float4* inr = (const float4*)(in + (size_t)row * D);
  float4 v = inr[tid];
  float ss = v.x * v.x + v.y * v.y + v.z * v.z + v.w * v.w;
#pragma unroll
  for (int off = 32; off >= 1; off >>= 1) ss += __shfl_xor(ss, off, 64);
  __shared__ float s4[4];
  if ((tid & 63) == 0) s4[tid >> 6] = ss;
  __syncthreads();
  float tot = s4[0] + s4[1] + s4[2] + s4[3];
  float scale = 16.f / fmaxf(sqrtf(tot), 1e-12f);
  int w0 = __builtin_amdgcn_cvt_pk_fp8_f32(v.x * scale, v.y * scale, 0, false);
  w0 = __builtin_amdgcn_cvt_pk_fp8_f32(v.z * scale, v.w * scale, w0, true);
  const int k0 = tid * 4;
  const int doff = ((k0 >> 6) << 6) + (((k0 >> 3) & 3) << 4) +
                   (((k0 >> 5) & 1) << 3) + (k0 & 7);
  *(int*)(out + (size_t)row * D + doff) = w0;
}

// ------- fused fp8 GEMM (xn.wn^T) + harmonic-softmax partials -------
// 256x256 tile, 8 waves (2Mx4N), BK=64, 3-ring LDS (16KB chunks).
// 2 phases/K-tile; each phase's ds_reads feed the NEXT phase's MFMA
// (1-ahead register pipeline). Explicit lgkmcnt(4/8)+sched_barrier (rule #18).
// vmcnt cert placed BEFORE the barrier preceding the dependent reads
// (cross-wave-safe). Counted vmcnt only (4/0), never 0 mid-loop.
//
// LDS chunk layout ([256r x 64k] fp8): byte(r, unit) = r*64 + u*16 (+0..15),
//   u = kq ^ ((r>>1)&3). Read: ds_read_b128 at R*64 + (kq^((fcol>>1)&3))*16
//   -> 16 lanes hit 8 distinct 16B slots x 2 lanes = conflict-free (R4 class).
// Write: gl_lds16 linear dest; lane ln sources global unit kq=(ln&3)^((ln>>3)&3)
//   (16B contiguous thanks to frag-packed global layout). Round-trip verified.
__global__ __launch_bounds__(512, 2) void k_gemm_lse(
    const unsigned char* __restrict__ xnb,
    const unsigned char* __restrict__ wnb,
    const int* __restrict__ tgt,
    float* __restrict__ parts,
    float* __restrict__ tlp,
    int M, int C, int D, int ntN) {
  __shared__ __align__(16) unsigned char sA[3][16384];
  __shared__ __align__(16) unsigned char sB[3][16384];
  __shared__ int s_tgt[256];

  const int ntM = M >> 8;               // 16
  const int nwg = ntM * ntN;            // 2000 (div by 8)
  const int orig = blockIdx.x;
  const int cpx = nwg >> 3;
  const int bid = (orig & 7) * cpx + (orig >> 3);   // bijective XCD swizzle
  const int tileM = bid % ntM;
  const int tileN = bid / ntM;
  const int row0 = tileM << 8;
  const int c0 = tileN << 8;

  const int tid = threadIdx.x;
  const int lane = tid & 63;
  const int wid = tid >> 6;
  const int wr = wid >> 2;              // M-half
  const int wc = wid & 3;               // N-quarter
  const int fcol = lane & 15;
  const int kq = lane >> 4;

  if (tid < 256) s_tgt[tid] = tgt[row0 + tid];

  // staging lane constants (rule #21 decode)
  const int srow_l = lane >> 2;                               // +wid*16 (+128)
  const int scol_l = (((lane & 3) ^ ((lane >> 3) & 3)) << 4); // global unit byte
  const int lane16 = lane << 4;
  const size_t Dz = (size_t)D;  // row stride in bytes

#define STAGE(dst, mat, rb, kb)                                                \
  do {                                                                         \
    gl_lds16((mat) + (size_t)((rb) + (wid << 4) + srow_l) * Dz + (kb) + scol_l,\
             (dst) + (wid << 10) + lane16);                                    \
    gl_lds16((mat) + (size_t)((rb) + 128 + (wid << 4) + srow_l) * Dz + (kb) +  \
                 scol_l,                                                       \
             (dst) + 8192 + (wid << 10) + lane16);                             \
  } while (0)

  // fragment read bases (bytes); per-frag stride 1024
  const int uL = ((fcol >> 1) & 3);
  const int abase = (wr * 128 + fcol) * 64 + ((kq ^ uL) << 4);
  const int bbase = (wc * 64 + fcol) * 64 + ((kq ^ uL) << 4);

  f32x4 acc[8][4];
#pragma unroll
  for (int m = 0; m < 8; ++m)
#pragma unroll
    for (int n = 0; n < 4; ++n) acc[m][n] = (f32x4){0.f, 0.f, 0.f, 0.f};

  l2v av0[4], av1[4], bv0[4], bv1[4];
  const int NT = D >> 6;  // 16

#define MFMAQ(AV, BV, MB)                                                      \
  do {                                                                         \
    _Pragma("unroll") for (int mm = 0; mm < 4; ++mm)                           \
        _Pragma("unroll") for (int n = 0; n < 4; ++n) acc[(MB) + mm][n] =      \
            __builtin_amdgcn_mfma_f32_16x16x32_fp8_fp8(AV[mm].x, BV[n].x,      \
                                                       acc[(MB) + mm][n], 0,   \
                                                       0, 0);                  \
    _Pragma("unroll") for (int mm = 0; mm < 4; ++mm)                           \
        _Pragma("unroll") for (int n = 0; n < 4; ++n) acc[(MB) + mm][n] =      \
            __builtin_amdgcn_mfma_f32_16x16x32_fp8_fp8(AV[mm].y, BV[n].y,      \
                                                       acc[(MB) + mm][n], 0,   \
                                                       0, 0);                  \
  } while (0)

#define TILE(t, BC, BN)                                                        \
  do {                                                                         \
    const int rb_ = (t) % 3;                                                   \
    const unsigned char* pA_ = sA[rb_];                                        \
    /* ---- P0: consume (av0,BC); prefetch av1; stage t+2; cert t+1 ---- */    \
    if ((t) + 2 < NT) {                                                        \
      const int rs_ = ((t) + 2) % 3;                                           \
      STAGE(sA[rs_], xnb, row0, ((t) + 2) * 64);                               \
      STAGE(sB[rs_], wnb, c0, ((t) + 2) * 64);                                 \
    }                                                                          \
    _Pragma("unroll") for (int mm = 0; mm < 4; ++mm)                           \
        av1[mm] = *(const l2v*)(pA_ + abase + (4 + mm) * 1024);                \
    BAR();                                                                     \
    asm volatile("s_waitcnt lgkmcnt(4)" ::: "memory");                         \
    __builtin_amdgcn_sched_barrier(0);                                         \
    __builtin_amdgcn_s_setprio(1);                                             \
    MFMAQ(av0, BC, 0);                                                         \
    __builtin_amdgcn_s_setprio(0);                                             \
    if ((t) + 1 < NT) {                                                        \
      if ((t) + 2 < NT) VM4();                                                 \
      else VM0();                                                              \
    }                                                                          \
    BAR();                                                                     \
    /* ---- P1: consume (av1,BC); prefetch av0,BN for tile t+1 ---- */         \
    if ((t) + 1 < NT) {                                                        \
      const int rn_ = ((t) + 1) % 3;                                           \
      const unsigned char* pAn_ = sA[rn_];                                     \
      const unsigned char* pBn_ = sB[rn_];                                     \
      _Pragma("unroll") for (int mm = 0; mm < 4; ++mm)                         \
          av0[mm] = *(const l2v*)(pAn_ + abase + mm * 1024);                   \
      _Pragma("unroll") for (int n = 0; n < 4; ++n)                            \
          BN[n] = *(const l2v*)(pBn_ + bbase + n * 1024);                      \
    }                                                                          \
    BAR();                                                                     \
    if ((t) + 1 < NT)                                                          \
      asm volatile("s_waitcnt lgkmcnt(8)" ::: "memory");                       \
    else                                                                       \
      asm volatile("s_waitcnt lgkmcnt(0)" ::: "memory");                       \
    __builtin_amdgcn_sched_barrier(0);                                         \
    __builtin_amdgcn_s_setprio(1);                                             \
    MFMAQ(av1, BC, 4);                                                         \
    __builtin_amdgcn_s_setprio(0);                                             \
    BAR();                                                                     \
  } while (0)

  // prologue: stage tiles 0,1; cert tile0 (VM4 before BAR -> cross-wave safe);
  // initial reads for tile0 P0.
  STAGE(sA[0], xnb, row0, 0);
  STAGE(sB[0], wnb, c0, 0);
  STAGE(sA[1], xnb, row0, 64);
  STAGE(sB[1], wnb, c0, 64);
  VM4();
  BAR();
#pragma unroll
  for (int mm = 0; mm < 4; ++mm)
    av0[mm] = *(const l2v*)(sA[0] + abase + mm * 1024);
#pragma unroll
  for (int n = 0; n < 4; ++n)
    bv0[n] = *(const l2v*)(sB[0] + bbase + n * 1024);

  for (int tt = 0; tt < NT; tt += 2) {
    TILE(tt, bv0, bv1);
    TILE(tt + 1, bv1, bv0);
  }

  // ---- epilogue: se-term = (2-2s)^-5 (= d^-10, eps negligible); no max ----
  // C/D: col = fcol, row = kq*4 + j per 16x16 fragment.
#pragma unroll
  for (int m = 0; m < 8; ++m) {
#pragma unroll
    for (int j = 0; j < 4; ++j) {
      const int rl = wr * 128 + m * 16 + kq * 4 + j;
      const int grow = row0 + rl;
      const int trow = s_tgt[rl];
      float se = 0.f;
#pragma unroll
      for (int n = 0; n < 4; ++n) {
        // acc = 256*sim ; t2 = 2 - 2*sim
        float t2 = fmaxf(fmaf(acc[m][n][j], -1.f / 128.f, 2.f), 1e-6f);
        float r = hw_rcp(t2);
        float r2 = r * r;
        float r4 = r2 * r2;
        float p10 = r4 * r;  // t2^-5 = d^-10
        se += p10;
        int col = c0 + wc * 64 + n * 16 + fcol;
        if (col == trow) {
          // exact log-domain target value (matches reference eps placement)
          tlp[grow] = (-HEXP * LN2) * hw_log2(sqrtf(t2) + 1e-8f);
        }
      }
#pragma unroll
      for (int off = 8; off >= 1; off >>= 1) se += __shfl_xor(se, off, 64);
      if (fcol == 0) parts[(size_t)grow * (ntN * 4) + tileN * 4 + wc] = se;
    }
  }
}

// ---------------- per-row sum of linear partials + loss ----------------
__global__ __launch_bounds__(256) void k_combine(const float* __restrict__ parts,
                                                 const float* __restrict__ tlp,
                                                 float* __restrict__ rloss, int P) {
  const int row = blockIdx.x;
  const int tid = threadIdx.x;
  const float* p = parts + (size_t)row * P;
  float s = 0.f;
  for (int i = tid; i < P; i += 256) s += p[i];
#pragma unroll
  for (int off = 32; off >= 1; off >>= 1) s += __shfl_xor(s, off, 64);
  __shared__ float ssum[4];
  if ((tid & 63) == 0) ssum[tid >> 6] = s;
  __syncthreads();
  if (tid == 0) {
    float tot = ssum[0] + ssum[1] + ssum[2] + ssum[3];
    float lse = hw_log2(tot) * LN2;
    float pt = hw_exp2((tlp[row] - lse) * RLN2);
    rloss[row] = -hw_log2(pt + 1e-8f) * LN2;
  }
}

// ---------------- mean over rows ----------------
__global__ __launch_bounds__(256) void k_mean(const float* __restrict__ rloss,
                                              float* __restrict__ out, int B) {
  const int tid = threadIdx.x;
  double s = 0.0;
  for (int i = tid; i < B; i += 256) s += (double)rloss[i];
#pragma unroll
  for (int off = 32; off >= 1; off >>= 1) s += __shfl_xor(s, off, 64);
  __shared__ double sd[4];
  if ((tid & 63) == 0) sd[tid >> 6] = s;
  __syncthreads();
  if (tid == 0) out[0] = (float)((sd[0] + sd[1] + sd[2] + sd[3]) / (double)B);
}

extern "C" void kernel_launch(void* const* d_in, const int* in_sizes, int n_in,
                              void* d_out, int out_size, void* d_ws, size_t ws_size,
                              hipStream_t stream) {
  const float* x = (const float*)d_in[0];
  const float* w = (const float*)d_in[1];
  const int* tg = (const int*)d_in[2];
  const int B = in_sizes[2];
  const int D = in_sizes[0] / B;       // 1024
  const int C = in_sizes[1] / D;       // 32000
  const int ntN = C / 256;             // 125

  char* ws = (char*)d_ws;
  unsigned char* xnb = (unsigned char*)ws;                   // B*D fp8
  unsigned char* wnb = xnb + (size_t)B * D;                  // C*D fp8
  size_t off = (size_t)B * D + (size_t)C * D;
  off = (off + 255) & ~(size_t)255;
  float* parts = (float*)(ws + off);                         // B * ntN * 4
  off += (size_t)B * ntN * 4 * sizeof(float);
  float* tlp = (float*)(ws + off);                           // B
  off += (size_t)B * sizeof(float);
  float* rloss = (float*)(ws + off);                         // B

  k_rownorm<<<B, 256, 0, stream>>>(x, xnb, D);
  k_rownorm<<<C, 256, 0, stream>>>(w, wnb, D);
  k_gemm_lse<<<(B / 256) * ntN, 512, 0, stream>>>(xnb, wnb, tg, parts, tlp, B, C, D, ntN);
  k_combine<<<B, 256, 0, stream>>>(parts, tlp, rloss, ntN * 4);
  k_mean<<<1, 256, 0, stream>>>(rloss, (float*)d_out, B);
}